// Round 9
// baseline (132.619 us; speedup 1.0000x reference)
//
#include <hip/hip_runtime.h>
#include <cstddef>
#include <cstdint>

#define N_NODES 50000
#define N_EDGES 800000
#define D 128
#define BN_EPS 1e-5f

#define NSHARD 8
#define SHARD_N 6250                 // nodes per shard
#define SLOTS 48                     // fixed slots per node (Poisson(16): P(deg>=49)~1e-11)
#define BIN_CHUNKS 256               // 256*3125 = 800000
#define CHUNK_E 3125
#define BIN_BLOCKS (NSHARD * BIN_CHUNKS)          // 2048
#define CAST_ITEMS (N_NODES * D / 8 + D * D / 8)  // 802,048 octet jobs
#define CAST_BLOCKS ((CAST_ITEMS + 255) / 256)    // 3133
#define GEMM_CHUNKS 1563             // ceil(50000/32)
#define GEMM_GRID   512
#define FEAT_V8     (N_NODES * D / 8)   // 800,000
#define W_V8        (D * D / 8)         // 2,048
#define EDGE_V8     (N_EDGES / 8)       // 100,000 ushort8 octets per index array
#define ZERO_V4     12608               // int4s covering [0, WS_WB_OFF)

typedef __attribute__((ext_vector_type(8))) short short8_t;        // 8 x bf16 (mfma operand)
typedef __attribute__((ext_vector_type(8))) unsigned short u16x8;  // 8 x u16 storage
typedef __attribute__((ext_vector_type(4))) float f32x4;
typedef __attribute__((ext_vector_type(4))) int i32x4;

// ---------------- ws layout (bytes) ----------------
// cursor/deg : int[50000]        @ 0          (200,000)
// stats      : 2 x float[128]    @ 200,704    (1,024)
// wb (bf16 W): u16[16384]        @ 201,728    (32,768)
// dst16      : u16[800000]       @ 234,496    (1,600,000)
// src16      : u16[800000]       @ 1,834,496  (1,600,000)
// ebuf2      : u16[50000*48]     @ 3,434,496  (4,800,000)
// fb (bf16 X): u16[50000*128]    @ 8,234,496  (12,800,000)   total ~21.0 MB
#define WS_CURSOR_OFF  0
#define WS_STAT_OFF    200704
#define WS_WB_OFF      201728
#define WS_DST16_OFF   234496
#define WS_SRC16_OFF   1834496
#define WS_EBUF_OFF    3434496
#define WS_FB_OFF      8234496

static __device__ __forceinline__ unsigned short f2bf(float x) {
    unsigned u = __float_as_uint(x);
    unsigned r = (u + 0x7fffu + ((u >> 16) & 1u)) >> 16;   // RNE
    return (unsigned short)r;
}
static __device__ __forceinline__ float bf2f(unsigned short v) {
    return __uint_as_float(((unsigned)v) << 16);
}

// Prep: zero cursor+stats, and compress src/dst to u16 (ids < 50000 < 65536).
__global__ __launch_bounds__(256) void prep_k(const int* __restrict__ src,
                                              const int* __restrict__ dst,
                                              u16x8* __restrict__ src16,
                                              u16x8* __restrict__ dst16,
                                              i32x4* __restrict__ zws) {
    int i = blockIdx.x * 256 + threadIdx.x;
    if (i < EDGE_V8 * 2) {
        const i32x4* sp = reinterpret_cast<const i32x4*>(i < EDGE_V8 ? dst : src);
        u16x8* dp = (i < EDGE_V8) ? dst16 : src16;
        int j = (i < EDGE_V8) ? i : i - EDGE_V8;
        i32x4 a = __builtin_nontemporal_load(sp + j * 2);
        i32x4 b = __builtin_nontemporal_load(sp + j * 2 + 1);
        u16x8 o;
        o[0] = (unsigned short)a.x; o[1] = (unsigned short)a.y;
        o[2] = (unsigned short)a.z; o[3] = (unsigned short)a.w;
        o[4] = (unsigned short)b.x; o[5] = (unsigned short)b.y;
        o[6] = (unsigned short)b.z; o[7] = (unsigned short)b.w;
        dp[j] = o;
    } else {
        int z = i - EDGE_V8 * 2;
        if (z < ZERO_V4) {
            i32x4 zero = (i32x4){0, 0, 0, 0};
            __builtin_nontemporal_store(zero, zws + z);
        }
    }
}

// Fused XCD-sharded binning + bf16 cast (block-role split).
// Blocks [0, BIN_BLOCKS): shard s=b&7 (XCD-aligned), chunk b>>3; bins edges
//   with dst in the shard's slice -> cursor/ebuf2 stay in that XCD's L2.
//   Streaming index reads are non-temporal to avoid evicting the slice.
// Blocks [BIN_BLOCKS, ...): cast feature/W to bf16 (nt loads/stores).
__global__ __launch_bounds__(256) void bincast_k(const unsigned short* __restrict__ src16,
                                                 const unsigned short* __restrict__ dst16,
                                                 int* __restrict__ cursor,
                                                 unsigned short* __restrict__ ebuf2,
                                                 const float* __restrict__ feat,
                                                 const float* __restrict__ W,
                                                 u16x8* __restrict__ fb,
                                                 u16x8* __restrict__ wb) {
    if (blockIdx.x < BIN_BLOCKS) {
        const int s     = blockIdx.x & 7;
        const int chunk = blockIdx.x >> 3;          // 0..255
        const int lo = s * SHARD_N, hi = lo + SHARD_N;
        const int base = chunk * CHUNK_E;
        const int end  = base + CHUNK_E;
        for (int e = base + threadIdx.x; e < end; e += 256) {
            int d = (int)__builtin_nontemporal_load(dst16 + e);
            if (d >= lo && d < hi) {
                int k = atomicAdd(cursor + d, 1);
                if (k < SLOTS)
                    ebuf2[d * SLOTS + k] = __builtin_nontemporal_load(src16 + e);
            }
        }
    } else {
        int i = (blockIdx.x - BIN_BLOCKS) * 256 + threadIdx.x;
        const float* sp; u16x8* dp; int j;
        if (i < FEAT_V8)             { sp = feat; dp = fb; j = i; }
        else if (i < FEAT_V8 + W_V8) { sp = W;    dp = wb; j = i - FEAT_V8; }
        else return;
        const f32x4* fp = reinterpret_cast<const f32x4*>(sp);
        f32x4 x0 = __builtin_nontemporal_load(fp + j * 2);
        f32x4 x1 = __builtin_nontemporal_load(fp + j * 2 + 1);
        u16x8 o;
        o[0] = f2bf(x0.x); o[1] = f2bf(x0.y); o[2] = f2bf(x0.z); o[3] = f2bf(x0.w);
        o[4] = f2bf(x1.x); o[5] = f2bf(x1.y); o[6] = f2bf(x1.z); o[7] = f2bf(x1.w);
        __builtin_nontemporal_store(o, dp + j);
    }
}

// One wave per node, sharded to match bincast's XCD slices. bf16 rows;
// quarter q handles edge e+q; lane covers 8 cols via one 16B load.
__global__ __launch_bounds__(256) void gather_k(const u16x8* __restrict__ fb,
                                                const int* __restrict__ cursor,
                                                const unsigned short* __restrict__ ebuf2,
                                                float* __restrict__ h) {
    const int s   = blockIdx.x & 7;
    const int q4  = blockIdx.x >> 3;             // 0..1562
    const int wav = threadIdx.x >> 6;
    const int idx = q4 * 4 + wav;
    if (idx >= SHARD_N) return;
    const int node = s * SHARD_N + idx;
    const int lane = threadIdx.x & 63;
    const int q = lane >> 4;             // quarter 0..3
    const int c = lane & 15;             // col octet: cols [c*8, c*8+8)
    const int deg = cursor[node];
    const int nd  = min(deg, SLOTS);
    const unsigned short* slots = ebuf2 + node * SLOTS;

    float a[8];
#pragma unroll
    for (int i = 0; i < 8; ++i) a[i] = 0.f;

    int e = 0;
    for (; e + 8 <= nd; e += 8) {
        int sA = slots[e + q];
        int sB = slots[e + 4 + q];
        u16x8 vA = fb[sA * 16 + c];
        u16x8 vB = fb[sB * 16 + c];
#pragma unroll
        for (int i = 0; i < 8; ++i) a[i] += bf2f(vA[i]) + bf2f(vB[i]);
    }
    if (e + q < nd) {
        u16x8 v = fb[(int)slots[e + q] * 16 + c];
#pragma unroll
        for (int i = 0; i < 8; ++i) a[i] += bf2f(v[i]);
    }
    if (e + 4 + q < nd) {
        u16x8 v = fb[(int)slots[e + 4 + q] * 16 + c];
#pragma unroll
        for (int i = 0; i < 8; ++i) a[i] += bf2f(v[i]);
    }

#pragma unroll
    for (int i = 0; i < 8; ++i) {
        a[i] += __shfl_xor(a[i], 16);
        a[i] += __shfl_xor(a[i], 32);
    }
    if (lane < 16) {
        float inv = (deg > 0) ? 1.f / (float)deg : 0.f;
        float4 o0, o1;
        o0.x = a[0] * inv; o0.y = a[1] * inv; o0.z = a[2] * inv; o0.w = a[3] * inv;
        o1.x = a[4] * inv; o1.y = a[5] * inv; o1.z = a[6] * inv; o1.w = a[7] * inv;
        float4* row = reinterpret_cast<float4*>(h + (size_t)node * D + lane * 8);
        row[0] = o0;
        row[1] = o1;
    }
}

// MFMA GEMM in-place over f32 agg (d_out): h = agg @ W^T + b, + column stats.
__global__ __launch_bounds__(256) void gemm_mfma_k(float* __restrict__ h,
                                                   const u16x8* __restrict__ wb,
                                                   const float* __restrict__ bias,
                                                   float* __restrict__ colsum,
                                                   float* __restrict__ colsumsq) {
    const int wave = threadIdx.x >> 6;
    const int lane = threadIdx.x & 63;
    const int wm = wave >> 1, wn = wave & 1;
    const int l15 = lane & 15, l4 = lane >> 4;

    short8_t bf[4][4];
#pragma unroll
    for (int t = 0; t < 4; ++t) {
        const int col = wn * 64 + t * 16 + l15;
#pragma unroll
        for (int s = 0; s < 4; ++s) {
            u16x8 w = wb[col * 16 + s * 4 + l4];
            short8_t b8;
#pragma unroll
            for (int i = 0; i < 8; ++i) b8[i] = (short)w[i];
            bf[t][s] = b8;
        }
    }
    float bc[4];
#pragma unroll
    for (int t = 0; t < 4; ++t) bc[t] = bias[wn * 64 + t * 16 + l15];

    float s1[4] = {0.f, 0.f, 0.f, 0.f};
    float s2[4] = {0.f, 0.f, 0.f, 0.f};

    for (int chunk = blockIdx.x; chunk < GEMM_CHUNKS; chunk += gridDim.x) {
        const int rbase = chunk * 32 + wm * 16;
        const int arow = min(rbase + l15, N_NODES - 1);
        const float* ap = h + (size_t)arow * D + l4 * 8;
        short8_t af[4];
#pragma unroll
        for (int s = 0; s < 4; ++s) {
            float4 x0 = *reinterpret_cast<const float4*>(ap + s * 32);
            float4 x1 = *reinterpret_cast<const float4*>(ap + s * 32 + 4);
            short8_t t8;
            t8[0] = (short)f2bf(x0.x); t8[1] = (short)f2bf(x0.y);
            t8[2] = (short)f2bf(x0.z); t8[3] = (short)f2bf(x0.w);
            t8[4] = (short)f2bf(x1.x); t8[5] = (short)f2bf(x1.y);
            t8[6] = (short)f2bf(x1.z); t8[7] = (short)f2bf(x1.w);
            af[s] = t8;
        }
        __syncthreads();               // all A-reads done before any store

        f32x4 acc[4];
#pragma unroll
        for (int t = 0; t < 4; ++t) acc[t] = (f32x4){0.f, 0.f, 0.f, 0.f};

#pragma unroll
        for (int s = 0; s < 4; ++s)
#pragma unroll
            for (int t = 0; t < 4; ++t)
                acc[t] = __builtin_amdgcn_mfma_f32_16x16x32_bf16(af[s], bf[t][s],
                                                                 acc[t], 0, 0, 0);

        const int orow0 = rbase + l4 * 4;
#pragma unroll
        for (int t = 0; t < 4; ++t) {
            const int col = wn * 64 + t * 16 + l15;
#pragma unroll
            for (int r = 0; r < 4; ++r) {
                const int row = orow0 + r;
                if (row < N_NODES) {
                    float hv = acc[t][r] + bc[t];
                    h[(size_t)row * D + col] = hv;
                    s1[t] += hv;
                    s2[t] += hv * hv;
                }
            }
        }
    }

#pragma unroll
    for (int t = 0; t < 4; ++t) {
        s1[t] += __shfl_xor(s1[t], 16); s1[t] += __shfl_xor(s1[t], 32);
        s2[t] += __shfl_xor(s2[t], 16); s2[t] += __shfl_xor(s2[t], 32);
    }
    if (lane < 16) {
#pragma unroll
        for (int t = 0; t < 4; ++t) {
            int col = wn * 64 + t * 16 + lane;
            atomicAdd(colsum + col, s1[t]);
            atomicAdd(colsumsq + col, s2[t]);
        }
    }
}

// out = feature + relu((h - mu) * rstd * gamma + beta), BN finalize fused.
__global__ __launch_bounds__(256) void epilogue_k(float* __restrict__ h,
                                                  const float* __restrict__ feat,
                                                  const float* __restrict__ colsum,
                                                  const float* __restrict__ colsumsq,
                                                  const float* __restrict__ gamma,
                                                  const float* __restrict__ beta) {
    int idx = blockIdx.x * blockDim.x + threadIdx.x;      // float4 index
    const int total = N_NODES * D / 4;
    if (idx >= total) return;
    int colb = (idx * 4) & 127;
    const float4 s1 = *reinterpret_cast<const float4*>(colsum + colb);
    const float4 s2 = *reinterpret_cast<const float4*>(colsumsq + colb);
    const float4 g  = *reinterpret_cast<const float4*>(gamma + colb);
    const float4 bt = *reinterpret_cast<const float4*>(beta + colb);
    const float inv_n = 1.0f / N_NODES;

    float4 a, bb;
    {
        float mu = s1.x * inv_n, var = s2.x * inv_n - mu * mu;
        float r = g.x * rsqrtf(var + BN_EPS); a.x = r; bb.x = bt.x - mu * r;
        mu = s1.y * inv_n; var = s2.y * inv_n - mu * mu;
        r = g.y * rsqrtf(var + BN_EPS); a.y = r; bb.y = bt.y - mu * r;
        mu = s1.z * inv_n; var = s2.z * inv_n - mu * mu;
        r = g.z * rsqrtf(var + BN_EPS); a.z = r; bb.z = bt.z - mu * r;
        mu = s1.w * inv_n; var = s2.w * inv_n - mu * mu;
        r = g.w * rsqrtf(var + BN_EPS); a.w = r; bb.w = bt.w - mu * r;
    }

    float4 hv = reinterpret_cast<float4*>(h)[idx];
    float4 fv = reinterpret_cast<const float4*>(feat)[idx];
    float4 o;
    o.x = fv.x + fmaxf(hv.x * a.x + bb.x, 0.f);
    o.y = fv.y + fmaxf(hv.y * a.y + bb.y, 0.f);
    o.z = fv.z + fmaxf(hv.z * a.z + bb.z, 0.f);
    o.w = fv.w + fmaxf(hv.w * a.w + bb.w, 0.f);
    reinterpret_cast<float4*>(h)[idx] = o;
}

extern "C" void kernel_launch(void* const* d_in, const int* in_sizes, int n_in,
                              void* d_out, int out_size, void* d_ws, size_t ws_size,
                              hipStream_t stream) {
    const float* feature = (const float*)d_in[0];
    const float* W       = (const float*)d_in[1];
    const float* b       = (const float*)d_in[2];
    const float* gamma   = (const float*)d_in[3];
    const float* beta    = (const float*)d_in[4];
    const int*   src     = (const int*)d_in[5];
    const int*   dst     = (const int*)d_in[6];
    float* out = (float*)d_out;

    char* ws = (char*)d_ws;
    int*            cursor   = (int*)(ws + WS_CURSOR_OFF);
    float*          colsum   = (float*)(ws + WS_STAT_OFF);
    float*          colsumsq = colsum + 128;
    u16x8*          wb       = (u16x8*)(ws + WS_WB_OFF);
    unsigned short* dst16    = (unsigned short*)(ws + WS_DST16_OFF);
    unsigned short* src16    = (unsigned short*)(ws + WS_SRC16_OFF);
    unsigned short* ebuf2    = (unsigned short*)(ws + WS_EBUF_OFF);
    u16x8*          fb       = (u16x8*)(ws + WS_FB_OFF);

    prep_k<<<(EDGE_V8 * 2 + ZERO_V4 + 255) / 256, 256, 0, stream>>>(
        src, dst, (u16x8*)src16, (u16x8*)dst16, (i32x4*)ws);
    bincast_k<<<BIN_BLOCKS + CAST_BLOCKS, 256, 0, stream>>>(
        src16, dst16, cursor, ebuf2, feature, W, fb, wb);
    gather_k<<<NSHARD * ((SHARD_N + 3) / 4), 256, 0, stream>>>(fb, cursor, ebuf2, out);
    gemm_mfma_k<<<GEMM_GRID, 256, 0, stream>>>(out, wb, b, colsum, colsumsq);
    epilogue_k<<<(N_NODES * D / 4 + 255) / 256, 256, 0, stream>>>(
        out, feature, colsum, colsumsq, gamma, beta);
}

// Round 10
// 121.294 us; speedup vs baseline: 1.0934x; 1.0934x over previous
//
#include <hip/hip_runtime.h>
#include <cstddef>
#include <cstdint>

#define N_NODES 50000
#define N_EDGES 800000
#define D 128
#define BN_EPS 1e-5f

// Radix binning: bucket = dst >> 6 (64 nodes/bucket)
#define NBUCKET 782                  // 782*64 = 50048 >= 50000
#define BCAP 1536                    // per-bucket edge capacity (E[1023] + 16 sigma)
#define PASSA_BLOCKS 64
#define PASSA_CHUNK 12500            // 64 * 12500 = 800000
#define SLOTS 48                     // slots per node (Poisson(16): P(>=49) ~ 1e-11)
#define GEMM_CHUNKS 1563             // ceil(50000/32)
#define GEMM_GRID   512
#define FEAT_V8     (N_NODES * D / 8)   // 800,000
#define W_V8        (D * D / 8)         // 2,048
#define ZERO_V4     3192                // int4s covering stats+gcur [0, 51072)

typedef __attribute__((ext_vector_type(8))) short short8_t;        // 8 x bf16 (mfma operand)
typedef __attribute__((ext_vector_type(8))) unsigned short u16x8;  // 8 x u16 storage
typedef __attribute__((ext_vector_type(4))) float f32x4;
typedef __attribute__((ext_vector_type(4))) int i32x4;

// ---------------- ws layout (bytes) ----------------
// stats      : 2 x float[128]     @ 0           (1,024)
// gcur       : int[782*16] padded @ 1,024       (50,048)   [zeroed with stats]
// wb (bf16 W): u16[16384]         @ 51,072      (32,768)
// cursor/deg : int[50048]         @ 83,840      (200,192)  [fully overwritten]
// ebuf2      : u16[50048*48]      @ 284,032     (4,804,608)
// claims     : u32[782*1536]      @ 5,088,640   (4,804,608)
// fb (bf16 X): u16[50000*128]     @ 9,893,248   (12,800,000)   total ~22.7 MB
#define WS_STAT_OFF    0
#define WS_GCUR_OFF    1024
#define WS_WB_OFF      51072
#define WS_CURSOR_OFF  83840
#define WS_EBUF_OFF    284032
#define WS_CLAIM_OFF   5088640
#define WS_FB_OFF      9893248

static __device__ __forceinline__ unsigned short f2bf(float x) {
    unsigned u = __float_as_uint(x);
    unsigned r = (u + 0x7fffu + ((u >> 16) & 1u)) >> 16;   // RNE
    return (unsigned short)r;
}
static __device__ __forceinline__ float bf2f(unsigned short v) {
    return __uint_as_float(((unsigned)v) << 16);
}

// Cast feature and W to bf16; also zeroes stats + gcur (threads i < ZERO_V4).
__global__ __launch_bounds__(256) void cast_k(const float* __restrict__ feat,
                                              const float* __restrict__ W,
                                              u16x8* __restrict__ fb,
                                              u16x8* __restrict__ wb,
                                              i32x4* __restrict__ zws) {
    int i = blockIdx.x * 256 + threadIdx.x;
    if (i < ZERO_V4) {
        i32x4 zero = (i32x4){0, 0, 0, 0};
        __builtin_nontemporal_store(zero, zws + i);
    }
    const float* sp; u16x8* dp; int j;
    if (i < FEAT_V8)             { sp = feat; dp = fb; j = i; }
    else if (i < FEAT_V8 + W_V8) { sp = W;    dp = wb; j = i - FEAT_V8; }
    else return;
    const f32x4* fp = reinterpret_cast<const f32x4*>(sp);
    f32x4 x0 = __builtin_nontemporal_load(fp + j * 2);
    f32x4 x1 = __builtin_nontemporal_load(fp + j * 2 + 1);
    u16x8 o;
    o[0] = f2bf(x0.x); o[1] = f2bf(x0.y); o[2] = f2bf(x0.z); o[3] = f2bf(x0.w);
    o[4] = f2bf(x1.x); o[5] = f2bf(x1.y); o[6] = f2bf(x1.z); o[7] = f2bf(x1.w);
    __builtin_nontemporal_store(o, dp + j);
}

// Pass A: radix-partition edges into 782 fixed-capacity buckets by dst>>6.
// LDS-staged; one padded global atomic per (block,bucket) to claim a base;
// writes are ~64 B runs (16 edges avg per block-bucket).
__global__ __launch_bounds__(256) void partition_k(const int* __restrict__ src,
                                                   const int* __restrict__ dst,
                                                   int* __restrict__ gcur,
                                                   unsigned* __restrict__ claims) {
    __shared__ unsigned pk[PASSA_CHUNK];     // 50,000 B packed edges
    __shared__ int hist[NBUCKET];            // 3,128 B
    __shared__ int base_l[NBUCKET];          // 3,128 B
    const int t = threadIdx.x;
    const int base = blockIdx.x * PASSA_CHUNK;

    for (int b = t; b < NBUCKET; b += 256) hist[b] = 0;
    __syncthreads();

    for (int i = t; i < PASSA_CHUNK; i += 256) {
        int s = src[base + i];
        int d = dst[base + i];
        pk[i] = ((unsigned)s << 16) | (unsigned)d;
        atomicAdd(&hist[d >> 6], 1);
    }
    __syncthreads();

    for (int b = t; b < NBUCKET; b += 256) {
        int h = hist[b];
        base_l[b] = h ? atomicAdd(gcur + b * 16, h) : 0;
        hist[b] = 0;                         // reuse as running offset
    }
    __syncthreads();

    for (int i = t; i < PASSA_CHUNK; i += 256) {
        unsigned u = pk[i];
        int bkt = (int)(u & 0xffffu) >> 6;
        int k = atomicAdd(&hist[bkt], 1);
        int pos = base_l[bkt] + k;
        if (pos < BCAP) claims[bkt * BCAP + pos] = u;
    }
}

// Pass B: one block per bucket. Sequential read of the bucket's edges,
// LDS-atomic binning into a 64-node slot table, coalesced write-out of
// ebuf2 slice + cursor. No global atomics.
__global__ __launch_bounds__(256) void binwrite_k(const int* __restrict__ gcur,
                                                  const unsigned* __restrict__ claims,
                                                  int* __restrict__ cursor,
                                                  u16x8* __restrict__ ebuf2_v8) {
    __shared__ int lcnt[64];
    __shared__ unsigned short ebl[64 * SLOTS];   // 6,144 B
    const int t = threadIdx.x;
    const int b = blockIdx.x;

    if (t < 64) lcnt[t] = 0;
    __syncthreads();

    const int n = min(gcur[b * 16], BCAP);
    const unsigned* cp = claims + b * BCAP;
    for (int i = t; i < n; i += 256) {
        unsigned u = cp[i];
        int dl = (int)(u & 63u);
        int k = atomicAdd(&lcnt[dl], 1);
        if (k < SLOTS) ebl[dl * SLOTS + k] = (unsigned short)(u >> 16);
    }
    __syncthreads();

    // ebuf2 slice: 64 nodes * 48 u16 = 384 u16x8 octets, block base b*384
    const u16x8* el = reinterpret_cast<const u16x8*>(ebl);
    for (int o = t; o < 64 * SLOTS / 8; o += 256)
        ebuf2_v8[b * (64 * SLOTS / 8) + o] = el[o];
    if (t < 64) cursor[(b << 6) + t] = lcnt[t];
}

// One wave per node. bf16 rows; quarter q handles edge e+q; lane covers
// 8 cols via one 16B load.
__global__ __launch_bounds__(256) void gather_k(const u16x8* __restrict__ fb,
                                                const int* __restrict__ cursor,
                                                const unsigned short* __restrict__ ebuf2,
                                                float* __restrict__ h) {
    const int node = blockIdx.x * 4 + (threadIdx.x >> 6);
    const int lane = threadIdx.x & 63;
    const int q = lane >> 4;             // quarter 0..3
    const int c = lane & 15;             // col octet: cols [c*8, c*8+8)
    const int deg = cursor[node];
    const int nd  = min(deg, SLOTS);
    const unsigned short* slots = ebuf2 + node * SLOTS;

    float a[8];
#pragma unroll
    for (int i = 0; i < 8; ++i) a[i] = 0.f;

    int e = 0;
    for (; e + 8 <= nd; e += 8) {
        int sA = slots[e + q];
        int sB = slots[e + 4 + q];
        u16x8 vA = fb[sA * 16 + c];
        u16x8 vB = fb[sB * 16 + c];
#pragma unroll
        for (int i = 0; i < 8; ++i) a[i] += bf2f(vA[i]) + bf2f(vB[i]);
    }
    if (e + q < nd) {
        u16x8 v = fb[(int)slots[e + q] * 16 + c];
#pragma unroll
        for (int i = 0; i < 8; ++i) a[i] += bf2f(v[i]);
    }
    if (e + 4 + q < nd) {
        u16x8 v = fb[(int)slots[e + 4 + q] * 16 + c];
#pragma unroll
        for (int i = 0; i < 8; ++i) a[i] += bf2f(v[i]);
    }

#pragma unroll
    for (int i = 0; i < 8; ++i) {
        a[i] += __shfl_xor(a[i], 16);
        a[i] += __shfl_xor(a[i], 32);
    }
    if (lane < 16) {
        float inv = (deg > 0) ? 1.f / (float)deg : 0.f;
        float4 o0, o1;
        o0.x = a[0] * inv; o0.y = a[1] * inv; o0.z = a[2] * inv; o0.w = a[3] * inv;
        o1.x = a[4] * inv; o1.y = a[5] * inv; o1.z = a[6] * inv; o1.w = a[7] * inv;
        float4* row = reinterpret_cast<float4*>(h + (size_t)node * D + lane * 8);
        row[0] = o0;
        row[1] = o1;
    }
}

// MFMA GEMM in-place over f32 agg (d_out): h = agg @ W^T + b, + column stats.
__global__ __launch_bounds__(256) void gemm_mfma_k(float* __restrict__ h,
                                                   const u16x8* __restrict__ wb,
                                                   const float* __restrict__ bias,
                                                   float* __restrict__ colsum,
                                                   float* __restrict__ colsumsq) {
    const int wave = threadIdx.x >> 6;
    const int lane = threadIdx.x & 63;
    const int wm = wave >> 1, wn = wave & 1;
    const int l15 = lane & 15, l4 = lane >> 4;

    short8_t bf[4][4];
#pragma unroll
    for (int t = 0; t < 4; ++t) {
        const int col = wn * 64 + t * 16 + l15;
#pragma unroll
        for (int s = 0; s < 4; ++s) {
            u16x8 w = wb[col * 16 + s * 4 + l4];
            short8_t b8;
#pragma unroll
            for (int i = 0; i < 8; ++i) b8[i] = (short)w[i];
            bf[t][s] = b8;
        }
    }
    float bc[4];
#pragma unroll
    for (int t = 0; t < 4; ++t) bc[t] = bias[wn * 64 + t * 16 + l15];

    float s1[4] = {0.f, 0.f, 0.f, 0.f};
    float s2[4] = {0.f, 0.f, 0.f, 0.f};

    for (int chunk = blockIdx.x; chunk < GEMM_CHUNKS; chunk += gridDim.x) {
        const int rbase = chunk * 32 + wm * 16;
        const int arow = min(rbase + l15, N_NODES - 1);
        const float* ap = h + (size_t)arow * D + l4 * 8;
        short8_t af[4];
#pragma unroll
        for (int s = 0; s < 4; ++s) {
            float4 x0 = *reinterpret_cast<const float4*>(ap + s * 32);
            float4 x1 = *reinterpret_cast<const float4*>(ap + s * 32 + 4);
            short8_t t8;
            t8[0] = (short)f2bf(x0.x); t8[1] = (short)f2bf(x0.y);
            t8[2] = (short)f2bf(x0.z); t8[3] = (short)f2bf(x0.w);
            t8[4] = (short)f2bf(x1.x); t8[5] = (short)f2bf(x1.y);
            t8[6] = (short)f2bf(x1.z); t8[7] = (short)f2bf(x1.w);
            af[s] = t8;
        }
        __syncthreads();               // all A-reads done before any store

        f32x4 acc[4];
#pragma unroll
        for (int t = 0; t < 4; ++t) acc[t] = (f32x4){0.f, 0.f, 0.f, 0.f};

#pragma unroll
        for (int s = 0; s < 4; ++s)
#pragma unroll
            for (int t = 0; t < 4; ++t)
                acc[t] = __builtin_amdgcn_mfma_f32_16x16x32_bf16(af[s], bf[t][s],
                                                                 acc[t], 0, 0, 0);

        const int orow0 = rbase + l4 * 4;
#pragma unroll
        for (int t = 0; t < 4; ++t) {
            const int col = wn * 64 + t * 16 + l15;
#pragma unroll
            for (int r = 0; r < 4; ++r) {
                const int row = orow0 + r;
                if (row < N_NODES) {
                    float hv = acc[t][r] + bc[t];
                    h[(size_t)row * D + col] = hv;
                    s1[t] += hv;
                    s2[t] += hv * hv;
                }
            }
        }
    }

#pragma unroll
    for (int t = 0; t < 4; ++t) {
        s1[t] += __shfl_xor(s1[t], 16); s1[t] += __shfl_xor(s1[t], 32);
        s2[t] += __shfl_xor(s2[t], 16); s2[t] += __shfl_xor(s2[t], 32);
    }
    if (lane < 16) {
#pragma unroll
        for (int t = 0; t < 4; ++t) {
            int col = wn * 64 + t * 16 + lane;
            atomicAdd(colsum + col, s1[t]);
            atomicAdd(colsumsq + col, s2[t]);
        }
    }
}

// out = feature + relu((h - mu) * rstd * gamma + beta), BN finalize fused.
__global__ __launch_bounds__(256) void epilogue_k(float* __restrict__ h,
                                                  const float* __restrict__ feat,
                                                  const float* __restrict__ colsum,
                                                  const float* __restrict__ colsumsq,
                                                  const float* __restrict__ gamma,
                                                  const float* __restrict__ beta) {
    int idx = blockIdx.x * blockDim.x + threadIdx.x;      // float4 index
    const int total = N_NODES * D / 4;
    if (idx >= total) return;
    int colb = (idx * 4) & 127;
    const float4 s1 = *reinterpret_cast<const float4*>(colsum + colb);
    const float4 s2 = *reinterpret_cast<const float4*>(colsumsq + colb);
    const float4 g  = *reinterpret_cast<const float4*>(gamma + colb);
    const float4 bt = *reinterpret_cast<const float4*>(beta + colb);
    const float inv_n = 1.0f / N_NODES;

    float4 a, bb;
    {
        float mu = s1.x * inv_n, var = s2.x * inv_n - mu * mu;
        float r = g.x * rsqrtf(var + BN_EPS); a.x = r; bb.x = bt.x - mu * r;
        mu = s1.y * inv_n; var = s2.y * inv_n - mu * mu;
        r = g.y * rsqrtf(var + BN_EPS); a.y = r; bb.y = bt.y - mu * r;
        mu = s1.z * inv_n; var = s2.z * inv_n - mu * mu;
        r = g.z * rsqrtf(var + BN_EPS); a.z = r; bb.z = bt.z - mu * r;
        mu = s1.w * inv_n; var = s2.w * inv_n - mu * mu;
        r = g.w * rsqrtf(var + BN_EPS); a.w = r; bb.w = bt.w - mu * r;
    }

    float4 hv = reinterpret_cast<float4*>(h)[idx];
    float4 fv = reinterpret_cast<const float4*>(feat)[idx];
    float4 o;
    o.x = fv.x + fmaxf(hv.x * a.x + bb.x, 0.f);
    o.y = fv.y + fmaxf(hv.y * a.y + bb.y, 0.f);
    o.z = fv.z + fmaxf(hv.z * a.z + bb.z, 0.f);
    o.w = fv.w + fmaxf(hv.w * a.w + bb.w, 0.f);
    reinterpret_cast<float4*>(h)[idx] = o;
}

extern "C" void kernel_launch(void* const* d_in, const int* in_sizes, int n_in,
                              void* d_out, int out_size, void* d_ws, size_t ws_size,
                              hipStream_t stream) {
    const float* feature = (const float*)d_in[0];
    const float* W       = (const float*)d_in[1];
    const float* b       = (const float*)d_in[2];
    const float* gamma   = (const float*)d_in[3];
    const float* beta    = (const float*)d_in[4];
    const int*   src     = (const int*)d_in[5];
    const int*   dst     = (const int*)d_in[6];
    float* out = (float*)d_out;

    char* ws = (char*)d_ws;
    float*          colsum   = (float*)(ws + WS_STAT_OFF);
    float*          colsumsq = colsum + 128;
    int*            gcur     = (int*)(ws + WS_GCUR_OFF);
    u16x8*          wb       = (u16x8*)(ws + WS_WB_OFF);
    int*            cursor   = (int*)(ws + WS_CURSOR_OFF);
    unsigned short* ebuf2    = (unsigned short*)(ws + WS_EBUF_OFF);
    unsigned*       claims   = (unsigned*)(ws + WS_CLAIM_OFF);
    u16x8*          fb       = (u16x8*)(ws + WS_FB_OFF);

    cast_k<<<(FEAT_V8 + W_V8 + 255) / 256, 256, 0, stream>>>(feature, W, fb, wb,
                                                             (i32x4*)ws);
    partition_k<<<PASSA_BLOCKS, 256, 0, stream>>>(src, dst, gcur, claims);
    binwrite_k<<<NBUCKET, 256, 0, stream>>>(gcur, claims, cursor, (u16x8*)ebuf2);
    gather_k<<<N_NODES / 4, 256, 0, stream>>>(fb, cursor, ebuf2, out);
    gemm_mfma_k<<<GEMM_GRID, 256, 0, stream>>>(out, wb, b, colsum, colsumsq);
    epilogue_k<<<(N_NODES * D / 4 + 255) / 256, 256, 0, stream>>>(
        out, feature, colsum, colsumsq, gamma, beta);
}

// Round 11
// 113.207 us; speedup vs baseline: 1.1715x; 1.0714x over previous
//
#include <hip/hip_runtime.h>
#include <cstddef>
#include <cstdint>

#define N_NODES 50000
#define N_EDGES 800000
#define D 128
#define BN_EPS 1e-5f

// Radix binning: bucket = dst >> 6 (64 nodes/bucket)
#define NBUCKET 782                  // 782*64 = 50048 >= 50000
#define PART_BLOCKS 128
#define PART_CHUNK 6250              // 128 * 6250 = 800000 exact
#define SLOTS 48                     // slots per node (Poisson(16): P(>=49) ~ 1e-11)
#define GEMM_CHUNKS 1563             // ceil(50000/32)
#define GEMM_GRID   512
#define FEAT_V8     (N_NODES * D / 8)   // 800,000
#define W_V8        (D * D / 8)         // 2,048
#define CAST_BLOCKS ((FEAT_V8 + W_V8 + 255) / 256)   // 3133

typedef __attribute__((ext_vector_type(8))) short short8_t;        // 8 x bf16 (mfma operand)
typedef __attribute__((ext_vector_type(8))) unsigned short u16x8;  // 8 x u16 storage
typedef __attribute__((ext_vector_type(4))) float f32x4;
typedef __attribute__((ext_vector_type(4))) int i32x4;

// ---------------- ws layout (bytes) ----------------
// stats      : 2 x float[128]     @ 0           (1,024)
// wb (bf16 W): u16[16384]         @ 1,024       (32,768)
// bstart     : u16[128][783]      @ 33,792      (200,448)  [fully overwritten]
// claims     : u32[800000]        @ 234,240     (3,200,000) [fully overwritten]
// fb (bf16 X): u16[50000*128]     @ 3,434,240   (12,800,000)  total ~16.2 MB
#define WS_STAT_OFF    0
#define WS_WB_OFF      1024
#define WS_BSTART_OFF  33792
#define WS_CLAIM_OFF   234240
#define WS_FB_OFF      3434240

static __device__ __forceinline__ unsigned short f2bf(float x) {
    unsigned u = __float_as_uint(x);
    unsigned r = (u + 0x7fffu + ((u >> 16) & 1u)) >> 16;   // RNE
    return (unsigned short)r;
}
static __device__ __forceinline__ float bf2f(unsigned short v) {
    return __uint_as_float(((unsigned)v) << 16);
}

// Fused cast + atomic-free partition (block-role split).
// Blocks [0,128): partition role. LDS histogram -> LDS scan -> write own
//   contiguous claims segment (sorted by bucket) + bstart[p][b] u16 table.
// Blocks [128,...): cast feature/W to bf16; first block zeroes stats.
__global__ __launch_bounds__(256) void castpart_k(const float* __restrict__ feat,
                                                  const float* __restrict__ W,
                                                  u16x8* __restrict__ fb,
                                                  u16x8* __restrict__ wb,
                                                  const int* __restrict__ src,
                                                  const int* __restrict__ dst,
                                                  unsigned short* __restrict__ bstart,
                                                  unsigned* __restrict__ claims,
                                                  i32x4* __restrict__ zstat) {
    __shared__ unsigned pk[PART_CHUNK];      // 25,000 B
    __shared__ int hist[NBUCKET];            // 3,128 B
    __shared__ int tsum[256];                // 1,024 B
    const int t = threadIdx.x;

    if (blockIdx.x < PART_BLOCKS) {
        const int p = blockIdx.x;
        const int base = p * PART_CHUNK;

        for (int b = t; b < NBUCKET; b += 256) hist[b] = 0;
        __syncthreads();

        for (int i = t; i < PART_CHUNK; i += 256) {
            int s = src[base + i];
            int d = dst[base + i];
            pk[i] = ((unsigned)s << 16) | (unsigned)d;
            atomicAdd(&hist[d >> 6], 1);
        }
        __syncthreads();

        // exclusive scan of hist[0..782): thread t owns buckets 4t..4t+4
        int loc[4]; int s = 0;
#pragma unroll
        for (int j = 0; j < 4; ++j) {
            int b = 4 * t + j;
            loc[j] = (b < NBUCKET) ? hist[b] : 0;
            s += loc[j];
        }
        tsum[t] = s;
        __syncthreads();
#pragma unroll
        for (int off = 1; off < 256; off <<= 1) {
            int u = (t >= off) ? tsum[t - off] : 0;
            __syncthreads();
            tsum[t] += u;
            __syncthreads();
        }
        int run = tsum[t] - s;                    // exclusive base
#pragma unroll
        for (int j = 0; j < 4; ++j) {
            int b = 4 * t + j;
            if (b < NBUCKET) {
                hist[b] = run;
                bstart[p * (NBUCKET + 1) + b] = (unsigned short)run;
                run += loc[j];
            }
        }
        if (t == 255) bstart[p * (NBUCKET + 1) + NBUCKET] = (unsigned short)PART_CHUNK;
        __syncthreads();

        for (int i = t; i < PART_CHUNK; i += 256) {
            unsigned u = pk[i];
            int bkt = (int)(u & 0xffffu) >> 6;
            int k = atomicAdd(&hist[bkt], 1);
            claims[base + k] = u;
        }
    } else {
        int i = (blockIdx.x - PART_BLOCKS) * 256 + t;
        if (i < 64) {                             // zero stats (1 KB)
            i32x4 zero = (i32x4){0, 0, 0, 0};
            zstat[i] = zero;
        }
        const float* sp; u16x8* dp; int j;
        if (i < FEAT_V8)             { sp = feat; dp = fb; j = i; }
        else if (i < FEAT_V8 + W_V8) { sp = W;    dp = wb; j = i - FEAT_V8; }
        else return;
        const f32x4* fp = reinterpret_cast<const f32x4*>(sp);
        f32x4 x0 = __builtin_nontemporal_load(fp + j * 2);
        f32x4 x1 = __builtin_nontemporal_load(fp + j * 2 + 1);
        u16x8 o;
        o[0] = f2bf(x0.x); o[1] = f2bf(x0.y); o[2] = f2bf(x0.z); o[3] = f2bf(x0.w);
        o[4] = f2bf(x1.x); o[5] = f2bf(x1.y); o[6] = f2bf(x1.z); o[7] = f2bf(x1.w);
        __builtin_nontemporal_store(o, dp + j);
    }
}

// One block (1024 thr = 16 waves) per bucket: LDS-bin the bucket's edges from
// the 128 claims segments, then gather. No global atomics; no ebuf2 round-trip.
// Wave w: phase 1 reads segments [8w,8w+8); phase 2 gathers nodes 4w..4w+4.
__global__ __launch_bounds__(1024) void bingather_k(const unsigned short* __restrict__ bstart,
                                                    const unsigned* __restrict__ claims,
                                                    const u16x8* __restrict__ fb,
                                                    float* __restrict__ h) {
    __shared__ int lcnt[64];
    __shared__ unsigned short ebl[64 * SLOTS];   // 6,144 B
    const int t = threadIdx.x;
    const int b = blockIdx.x;
    const int wave = t >> 6;
    const int lane = t & 63;

    if (t < 64) lcnt[t] = 0;
    __syncthreads();

#pragma unroll
    for (int pp = 0; pp < 8; ++pp) {
        const int p = wave * 8 + pp;
        const int st = bstart[p * (NBUCKET + 1) + b];
        const int en = bstart[p * (NBUCKET + 1) + b + 1];
        for (int i = st + lane; i < en; i += 64) {
            unsigned u = claims[p * PART_CHUNK + i];
            int dl = (int)(u & 63u);
            int k = atomicAdd(&lcnt[dl], 1);
            if (k < SLOTS) ebl[dl * SLOTS + k] = (unsigned short)(u >> 16);
        }
    }
    __syncthreads();

    const int q = lane >> 4;             // quarter 0..3
    const int c = lane & 15;             // col octet: cols [c*8, c*8+8)
    for (int v = 0; v < 4; ++v) {
        const int nl = wave * 4 + v;     // node-local 0..63
        const int node = (b << 6) + nl;
        const int deg = lcnt[nl];
        const int nd  = min(deg, SLOTS);
        const unsigned short* slots = ebl + nl * SLOTS;

        float a[8];
#pragma unroll
        for (int i = 0; i < 8; ++i) a[i] = 0.f;

        int e = 0;
        for (; e + 8 <= nd; e += 8) {
            int sA = slots[e + q];
            int sB = slots[e + 4 + q];
            u16x8 vA = fb[sA * 16 + c];
            u16x8 vB = fb[sB * 16 + c];
#pragma unroll
            for (int i = 0; i < 8; ++i) a[i] += bf2f(vA[i]) + bf2f(vB[i]);
        }
        if (e + q < nd) {
            u16x8 v8 = fb[(int)slots[e + q] * 16 + c];
#pragma unroll
            for (int i = 0; i < 8; ++i) a[i] += bf2f(v8[i]);
        }
        if (e + 4 + q < nd) {
            u16x8 v8 = fb[(int)slots[e + 4 + q] * 16 + c];
#pragma unroll
            for (int i = 0; i < 8; ++i) a[i] += bf2f(v8[i]);
        }

#pragma unroll
        for (int i = 0; i < 8; ++i) {
            a[i] += __shfl_xor(a[i], 16);
            a[i] += __shfl_xor(a[i], 32);
        }
        if (lane < 16 && node < N_NODES) {
            float inv = (deg > 0) ? 1.f / (float)deg : 0.f;
            float4 o0, o1;
            o0.x = a[0] * inv; o0.y = a[1] * inv; o0.z = a[2] * inv; o0.w = a[3] * inv;
            o1.x = a[4] * inv; o1.y = a[5] * inv; o1.z = a[6] * inv; o1.w = a[7] * inv;
            float4* row = reinterpret_cast<float4*>(h + (size_t)node * D + lane * 8);
            row[0] = o0;
            row[1] = o1;
        }
    }
}

// MFMA GEMM in-place over f32 agg (d_out): h = agg @ W^T + b, + column stats.
__global__ __launch_bounds__(256) void gemm_mfma_k(float* __restrict__ h,
                                                   const u16x8* __restrict__ wb,
                                                   const float* __restrict__ bias,
                                                   float* __restrict__ colsum,
                                                   float* __restrict__ colsumsq) {
    const int wave = threadIdx.x >> 6;
    const int lane = threadIdx.x & 63;
    const int wm = wave >> 1, wn = wave & 1;
    const int l15 = lane & 15, l4 = lane >> 4;

    short8_t bf[4][4];
#pragma unroll
    for (int t = 0; t < 4; ++t) {
        const int col = wn * 64 + t * 16 + l15;
#pragma unroll
        for (int s = 0; s < 4; ++s) {
            u16x8 w = wb[col * 16 + s * 4 + l4];
            short8_t b8;
#pragma unroll
            for (int i = 0; i < 8; ++i) b8[i] = (short)w[i];
            bf[t][s] = b8;
        }
    }
    float bc[4];
#pragma unroll
    for (int t = 0; t < 4; ++t) bc[t] = bias[wn * 64 + t * 16 + l15];

    float s1[4] = {0.f, 0.f, 0.f, 0.f};
    float s2[4] = {0.f, 0.f, 0.f, 0.f};

    for (int chunk = blockIdx.x; chunk < GEMM_CHUNKS; chunk += gridDim.x) {
        const int rbase = chunk * 32 + wm * 16;
        const int arow = min(rbase + l15, N_NODES - 1);
        const float* ap = h + (size_t)arow * D + l4 * 8;
        short8_t af[4];
#pragma unroll
        for (int s = 0; s < 4; ++s) {
            float4 x0 = *reinterpret_cast<const float4*>(ap + s * 32);
            float4 x1 = *reinterpret_cast<const float4*>(ap + s * 32 + 4);
            short8_t t8;
            t8[0] = (short)f2bf(x0.x); t8[1] = (short)f2bf(x0.y);
            t8[2] = (short)f2bf(x0.z); t8[3] = (short)f2bf(x0.w);
            t8[4] = (short)f2bf(x1.x); t8[5] = (short)f2bf(x1.y);
            t8[6] = (short)f2bf(x1.z); t8[7] = (short)f2bf(x1.w);
            af[s] = t8;
        }
        __syncthreads();               // all A-reads done before any store

        f32x4 acc[4];
#pragma unroll
        for (int t = 0; t < 4; ++t) acc[t] = (f32x4){0.f, 0.f, 0.f, 0.f};

#pragma unroll
        for (int s = 0; s < 4; ++s)
#pragma unroll
            for (int t = 0; t < 4; ++t)
                acc[t] = __builtin_amdgcn_mfma_f32_16x16x32_bf16(af[s], bf[t][s],
                                                                 acc[t], 0, 0, 0);

        const int orow0 = rbase + l4 * 4;
#pragma unroll
        for (int t = 0; t < 4; ++t) {
            const int col = wn * 64 + t * 16 + l15;
#pragma unroll
            for (int r = 0; r < 4; ++r) {
                const int row = orow0 + r;
                if (row < N_NODES) {
                    float hv = acc[t][r] + bc[t];
                    h[(size_t)row * D + col] = hv;
                    s1[t] += hv;
                    s2[t] += hv * hv;
                }
            }
        }
    }

#pragma unroll
    for (int t = 0; t < 4; ++t) {
        s1[t] += __shfl_xor(s1[t], 16); s1[t] += __shfl_xor(s1[t], 32);
        s2[t] += __shfl_xor(s2[t], 16); s2[t] += __shfl_xor(s2[t], 32);
    }
    if (lane < 16) {
#pragma unroll
        for (int t = 0; t < 4; ++t) {
            int col = wn * 64 + t * 16 + lane;
            atomicAdd(colsum + col, s1[t]);
            atomicAdd(colsumsq + col, s2[t]);
        }
    }
}

// out = feature + relu((h - mu) * rstd * gamma + beta), BN finalize fused.
__global__ __launch_bounds__(256) void epilogue_k(float* __restrict__ h,
                                                  const float* __restrict__ feat,
                                                  const float* __restrict__ colsum,
                                                  const float* __restrict__ colsumsq,
                                                  const float* __restrict__ gamma,
                                                  const float* __restrict__ beta) {
    int idx = blockIdx.x * blockDim.x + threadIdx.x;      // float4 index
    const int total = N_NODES * D / 4;
    if (idx >= total) return;
    int colb = (idx * 4) & 127;
    const float4 s1 = *reinterpret_cast<const float4*>(colsum + colb);
    const float4 s2 = *reinterpret_cast<const float4*>(colsumsq + colb);
    const float4 g  = *reinterpret_cast<const float4*>(gamma + colb);
    const float4 bt = *reinterpret_cast<const float4*>(beta + colb);
    const float inv_n = 1.0f / N_NODES;

    float4 a, bb;
    {
        float mu = s1.x * inv_n, var = s2.x * inv_n - mu * mu;
        float r = g.x * rsqrtf(var + BN_EPS); a.x = r; bb.x = bt.x - mu * r;
        mu = s1.y * inv_n; var = s2.y * inv_n - mu * mu;
        r = g.y * rsqrtf(var + BN_EPS); a.y = r; bb.y = bt.y - mu * r;
        mu = s1.z * inv_n; var = s2.z * inv_n - mu * mu;
        r = g.z * rsqrtf(var + BN_EPS); a.z = r; bb.z = bt.z - mu * r;
        mu = s1.w * inv_n; var = s2.w * inv_n - mu * mu;
        r = g.w * rsqrtf(var + BN_EPS); a.w = r; bb.w = bt.w - mu * r;
    }

    float4 hv = reinterpret_cast<float4*>(h)[idx];
    float4 fv = reinterpret_cast<const float4*>(feat)[idx];
    float4 o;
    o.x = fv.x + fmaxf(hv.x * a.x + bb.x, 0.f);
    o.y = fv.y + fmaxf(hv.y * a.y + bb.y, 0.f);
    o.z = fv.z + fmaxf(hv.z * a.z + bb.z, 0.f);
    o.w = fv.w + fmaxf(hv.w * a.w + bb.w, 0.f);
    reinterpret_cast<float4*>(h)[idx] = o;
}

extern "C" void kernel_launch(void* const* d_in, const int* in_sizes, int n_in,
                              void* d_out, int out_size, void* d_ws, size_t ws_size,
                              hipStream_t stream) {
    const float* feature = (const float*)d_in[0];
    const float* W       = (const float*)d_in[1];
    const float* b       = (const float*)d_in[2];
    const float* gamma   = (const float*)d_in[3];
    const float* beta    = (const float*)d_in[4];
    const int*   src     = (const int*)d_in[5];
    const int*   dst     = (const int*)d_in[6];
    float* out = (float*)d_out;

    char* ws = (char*)d_ws;
    float*          colsum   = (float*)(ws + WS_STAT_OFF);
    float*          colsumsq = colsum + 128;
    u16x8*          wb       = (u16x8*)(ws + WS_WB_OFF);
    unsigned short* bstart   = (unsigned short*)(ws + WS_BSTART_OFF);
    unsigned*       claims   = (unsigned*)(ws + WS_CLAIM_OFF);
    u16x8*          fb       = (u16x8*)(ws + WS_FB_OFF);

    castpart_k<<<PART_BLOCKS + CAST_BLOCKS, 256, 0, stream>>>(
        feature, W, fb, wb, src, dst, bstart, claims, (i32x4*)ws);
    bingather_k<<<NBUCKET, 1024, 0, stream>>>(bstart, claims, fb, out);
    gemm_mfma_k<<<GEMM_GRID, 256, 0, stream>>>(out, wb, b, colsum, colsumsq);
    epilogue_k<<<(N_NODES * D / 4 + 255) / 256, 256, 0, stream>>>(
        out, feature, colsum, colsumsq, gamma, beta);
}